// Round 1
// baseline (1922.762 us; speedup 1.0000x reference)
//
#include <hip/hip_runtime.h>

#define NN   50000
#define NE   800000
#define INF  128
#define EF   32
#define OUTF 128
#define KDIM 288   // 128 (h) + 128 (sum_h) + 32 (sum_e)

// ---------------------------------------------------------------------------
// Prep: build fused matrix M (288x128) and bias vector c (128).
//   rows 0..127   : M[f][j]     = W_w[j][f]                  (h_dst term)
//   rows 128..287 : M[128+m][j] = sum_k weight[m][k]*W_w[j][128+k]  (h_neigh term)
//   c[j] = W_b[j] + bias[j]
// grid = 289 blocks x 128 threads
// ---------------------------------------------------------------------------
__global__ void prep_kernel(const float* __restrict__ weight,
                            const float* __restrict__ W_w,
                            const float* __restrict__ W_b,
                            const float* __restrict__ bias,
                            float* __restrict__ Mmat,
                            float* __restrict__ cvec) {
    __shared__ float wrow[OUTF];
    const int r = blockIdx.x;
    const int j = threadIdx.x;
    if (r < 128) {
        Mmat[r * OUTF + j] = W_w[j * 256 + r];
        return;
    }
    if (r == KDIM) {
        cvec[j] = W_b[j] + bias[j];
        return;
    }
    const int m = r - 128;
    wrow[j] = weight[m * OUTF + j];
    __syncthreads();
    float acc = 0.f;
#pragma unroll 8
    for (int k = 0; k < OUTF; ++k)
        acc += wrow[k] * W_w[j * 256 + 128 + k];
    Mmat[r * OUTF + j] = acc;
}

// ---------------------------------------------------------------------------
// Scatter h[src] into sum_h[dst]. 32 threads per edge, float4 per thread.
// grid = NE*32/256 = 100000 blocks
// ---------------------------------------------------------------------------
__global__ __launch_bounds__(256)
void scatter_h_kernel(const float* __restrict__ h,
                      const int* __restrict__ src,
                      const int* __restrict__ dst,
                      float* __restrict__ sum_h) {
    const int i = blockIdx.x * 256 + threadIdx.x;
    const int e = i >> 5;
    const int q = i & 31;
    const int s = src[e];
    const int d = dst[e];
    const float4 v = *(const float4*)(h + (size_t)s * INF + q * 4);
    float* o = sum_h + (size_t)d * INF + q * 4;
    atomicAdd(o + 0, v.x);
    atomicAdd(o + 1, v.y);
    atomicAdd(o + 2, v.z);
    atomicAdd(o + 3, v.w);
}

// ---------------------------------------------------------------------------
// Scatter eftr into sum_e[dst] + degree count. 8 threads per edge.
// grid = NE*8/256 = 25000 blocks
// ---------------------------------------------------------------------------
__global__ __launch_bounds__(256)
void scatter_e_kernel(const float* __restrict__ eftr,
                      const int* __restrict__ dst,
                      float* __restrict__ sum_e,
                      float* __restrict__ cnt) {
    const int i = blockIdx.x * 256 + threadIdx.x;
    const int e = i >> 3;
    const int q = i & 7;
    const int d = dst[e];
    const float4 v = *(const float4*)(eftr + (size_t)e * EF + q * 4);
    float* o = sum_e + (size_t)d * EF + q * 4;
    atomicAdd(o + 0, v.x);
    atomicAdd(o + 1, v.y);
    atomicAdd(o + 2, v.z);
    atomicAdd(o + 3, v.w);
    if (q == 0) atomicAdd(cnt + d, 1.f);
}

// ---------------------------------------------------------------------------
// Node GEMM: out[n][j] = sum_r X[n][r] * M[r][j] + c[j]
//   X[n][r] = h[n][r]                      r in [0,128)
//           = sum_h[n][r-128] * inv[n]     r in [128,256)
//           = sum_e[n][r-256] * inv[n]     r in [256,288)
// Tile: 64 nodes x 128 cols per block, 256 threads, thread = 8 nodes x 4 cols.
// LDS layout is k-major so operand reads are ds_read_b128.
// grid = ceil(NN/64) = 782
// ---------------------------------------------------------------------------
__global__ __launch_bounds__(256)
void node_gemm_kernel(const float* __restrict__ h,
                      const float* __restrict__ sum_h,
                      const float* __restrict__ sum_e,
                      const float* __restrict__ cnt,
                      const float* __restrict__ Mmat,
                      const float* __restrict__ cvec,
                      float* __restrict__ out) {
    __shared__ float Xs[32][64];    // [k][node]
    __shared__ float Ms[32][128];   // [k][col]
    __shared__ float invs[64];

    const int tid = threadIdx.x;
    const int n0 = blockIdx.x * 64;

    if (tid < 64) {
        const int n = n0 + tid;
        const float c = (n < NN) ? cnt[n] : 1.f;
        invs[tid] = 1.f / fmaxf(c, 1.f);
    }
    __syncthreads();

    const int lq = tid & 7;     // float4 group within 32-k chunk
    const int lr = tid >> 3;    // node 0..31 (plus +32 second half)
    const int tcol = tid & 31;  // col quad -> cols tcol*4..+3
    const int trow = tid >> 5;  // node octet -> nodes trow*8..+7

    float acc[8][4] = {};

    for (int kb = 0; kb < 9; ++kb) {
        // ---- stage X chunk (transposed into k-major LDS) ----
#pragma unroll
        for (int half = 0; half < 2; ++half) {
            const int nn = lr + half * 32;
            const int n = n0 + nn;
            float4 v = make_float4(0.f, 0.f, 0.f, 0.f);
            float scale = 1.f;
            if (n < NN) {
                const float* srcp;
                if (kb < 4) {
                    srcp = h + (size_t)n * INF + kb * 32;
                } else if (kb < 8) {
                    srcp = sum_h + (size_t)n * INF + (kb - 4) * 32;
                    scale = invs[nn];
                } else {
                    srcp = sum_e + (size_t)n * EF;
                    scale = invs[nn];
                }
                v = ((const float4*)srcp)[lq];
            }
            Xs[lq * 4 + 0][nn] = v.x * scale;
            Xs[lq * 4 + 1][nn] = v.y * scale;
            Xs[lq * 4 + 2][nn] = v.z * scale;
            Xs[lq * 4 + 3][nn] = v.w * scale;
        }
        // ---- stage M chunk: 32 rows x 128 cols = 1024 float4 ----
        {
            const float4* mg = (const float4*)(Mmat + (size_t)kb * 32 * OUTF);
            float4* ms = (float4*)(&Ms[0][0]);
#pragma unroll
            for (int t = 0; t < 4; ++t)
                ms[tid + t * 256] = mg[tid + t * 256];
        }
        __syncthreads();

#pragma unroll
        for (int kk = 0; kk < 32; ++kk) {
            const float4 a0 = *(const float4*)&Xs[kk][trow * 8];
            const float4 a1 = *(const float4*)&Xs[kk][trow * 8 + 4];
            const float4 bv = *(const float4*)&Ms[kk][tcol * 4];
            const float a[8] = {a0.x, a0.y, a0.z, a0.w, a1.x, a1.y, a1.z, a1.w};
            const float b[4] = {bv.x, bv.y, bv.z, bv.w};
#pragma unroll
            for (int i = 0; i < 8; ++i)
#pragma unroll
                for (int j = 0; j < 4; ++j)
                    acc[i][j] += a[i] * b[j];
        }
        __syncthreads();
    }

    const float4 cv = *(const float4*)&cvec[tcol * 4];
#pragma unroll
    for (int i = 0; i < 8; ++i) {
        const int n = n0 + trow * 8 + i;
        if (n < NN) {
            float4 o;
            o.x = acc[i][0] + cv.x;
            o.y = acc[i][1] + cv.y;
            o.z = acc[i][2] + cv.z;
            o.w = acc[i][3] + cv.w;
            *(float4*)&out[(size_t)n * OUTF + tcol * 4] = o;
        }
    }
}

extern "C" void kernel_launch(void* const* d_in, const int* in_sizes, int n_in,
                              void* d_out, int out_size, void* d_ws, size_t ws_size,
                              hipStream_t stream) {
    const float* h      = (const float*)d_in[0];
    const float* eftr   = (const float*)d_in[1];
    const float* weight = (const float*)d_in[2];
    const float* W_w    = (const float*)d_in[3];
    const float* W_b    = (const float*)d_in[4];
    const float* bias   = (const float*)d_in[5];
    const int*   src    = (const int*)d_in[6];
    const int*   dst    = (const int*)d_in[7];
    float* out = (float*)d_out;

    float* ws    = (float*)d_ws;
    float* sum_h = ws;                               // NN*128
    float* sum_e = sum_h + (size_t)NN * INF;         // NN*32
    float* cntv  = sum_e + (size_t)NN * EF;          // NN
    float* Mmat  = cntv + NN;                        // 288*128
    float* cvec  = Mmat + (size_t)KDIM * OUTF;       // 128

    // zero the accumulators (sum_h, sum_e, cnt are contiguous at ws start)
    const size_t zero_bytes = ((size_t)NN * INF + (size_t)NN * EF + NN) * sizeof(float);
    hipMemsetAsync(sum_h, 0, zero_bytes, stream);

    prep_kernel<<<KDIM + 1, 128, 0, stream>>>(weight, W_w, W_b, bias, Mmat, cvec);
    scatter_h_kernel<<<NE * 32 / 256, 256, 0, stream>>>(h, src, dst, sum_h);
    scatter_e_kernel<<<NE * 8 / 256, 256, 0, stream>>>(eftr, dst, sum_e, cntv);
    node_gemm_kernel<<<(NN + 63) / 64, 256, 0, stream>>>(h, sum_h, sum_e, cntv,
                                                         Mmat, cvec, out);
}

// Round 2
// 518.667 us; speedup vs baseline: 3.7071x; 3.7071x over previous
//
#include <hip/hip_runtime.h>

#define NN   50000
#define NE   800000
#define INF  128
#define EF   32
#define OUTF 128
#define KDIM 288   // 128 (h) + 128 (mean_h) + 32 (mean_e)

// ---------------------------------------------------------------------------
// Prep: build fused matrix M (288x128) and bias vector c (128).
//   rows 0..127   : M[f][j]     = W_w[j][f]                         (h_dst)
//   rows 128..287 : M[128+m][j] = sum_k weight[m][k]*W_w[j][128+k]  (h_neigh)
//   c[j] = W_b[j] + bias[j]
// ---------------------------------------------------------------------------
__global__ void prep_kernel(const float* __restrict__ weight,
                            const float* __restrict__ W_w,
                            const float* __restrict__ W_b,
                            const float* __restrict__ bias,
                            float* __restrict__ Mmat,
                            float* __restrict__ cvec) {
    __shared__ float wrow[OUTF];
    const int r = blockIdx.x;
    const int j = threadIdx.x;
    if (r < 128) {
        Mmat[r * OUTF + j] = W_w[j * 256 + r];
        return;
    }
    if (r == KDIM) {
        cvec[j] = W_b[j] + bias[j];
        return;
    }
    const int m = r - 128;
    wrow[j] = weight[m * OUTF + j];
    __syncthreads();
    float acc = 0.f;
#pragma unroll 8
    for (int k = 0; k < OUTF; ++k)
        acc += wrow[k] * W_w[j * 256 + 128 + k];
    Mmat[r * OUTF + j] = acc;
}

// ---------------------------------------------------------------------------
// CSR build step 1: histogram of dst into off[0..NN-1] (must be pre-zeroed)
// ---------------------------------------------------------------------------
__global__ __launch_bounds__(256)
void hist_kernel(const int* __restrict__ dst, int* __restrict__ off) {
    const int e = blockIdx.x * 256 + threadIdx.x;
    if (e < NE) atomicAdd(&off[dst[e]], 1);
}

// ---------------------------------------------------------------------------
// CSR build step 2: in-place exclusive scan of off[0..NN-1]. Single block.
// ---------------------------------------------------------------------------
__global__ __launch_bounds__(1024)
void scan_kernel(int* __restrict__ off) {
    __shared__ int buf[1024];
    __shared__ int carry;
    const int tid = threadIdx.x;
    if (tid == 0) carry = 0;
    __syncthreads();
    for (int base = 0; base < NN; base += 1024) {
        const int idx = base + tid;
        const int v = (idx < NN) ? off[idx] : 0;
        buf[tid] = v;
        __syncthreads();
        for (int ofs = 1; ofs < 1024; ofs <<= 1) {
            const int t = (tid >= ofs) ? buf[tid - ofs] : 0;
            __syncthreads();
            buf[tid] += t;
            __syncthreads();
        }
        const int excl = buf[tid] - v + carry;
        if (idx < NN) off[idx] = excl;
        __syncthreads();
        if (tid == 1023) carry += buf[1023];
        __syncthreads();
    }
}

// ---------------------------------------------------------------------------
// CSR build step 3: scatter edge ids. Self-destructing-cursor trick:
// after this kernel, off[d] == end offset of segment d (start = off[d-1]).
// ---------------------------------------------------------------------------
__global__ __launch_bounds__(256)
void scatter_ids_kernel(const int* __restrict__ dst,
                        int* __restrict__ off,
                        int* __restrict__ eo) {
    const int e = blockIdx.x * 256 + threadIdx.x;
    if (e < NE) {
        const int d = dst[e];
        const int pos = atomicAdd(&off[d], 1);
        eo[pos] = e;
    }
}

// ---------------------------------------------------------------------------
// Gather: one wave per node, sequential accumulation in registers — no float
// atomics. Writes mean_h (x128) and mean_e (x32) already scaled by 1/deg.
// 256-thread blocks = 4 waves = 4 nodes. grid = 12500.
// ---------------------------------------------------------------------------
__global__ __launch_bounds__(256)
void gather_kernel(const float* __restrict__ h,
                   const float* __restrict__ eftr,
                   const int* __restrict__ srcv,
                   const int* __restrict__ off,   // end offsets
                   const int* __restrict__ eo,
                   float* __restrict__ mean_h,
                   float* __restrict__ mean_e) {
    const int tid = threadIdx.x;
    const int lane = tid & 63;
    const int node = blockIdx.x * 4 + (tid >> 6);
    if (node >= NN) return;

    const int end = off[node];
    const int start = (node == 0) ? 0 : off[node - 1];

    float ax = 0.f, ay = 0.f, ae = 0.f;
    const float* hcol = h + lane * 2;

    int i = start;
    for (; i + 1 < end; i += 2) {
        const int e0 = eo[i];
        const int e1 = eo[i + 1];
        const int s0 = srcv[e0];
        const int s1 = srcv[e1];
        const float2 v0 = *(const float2*)(hcol + (size_t)s0 * INF);
        const float2 v1 = *(const float2*)(hcol + (size_t)s1 * INF);
        float e0v = 0.f, e1v = 0.f;
        if (lane < EF) {
            e0v = eftr[(size_t)e0 * EF + lane];
            e1v = eftr[(size_t)e1 * EF + lane];
        }
        ax += v0.x + v1.x;
        ay += v0.y + v1.y;
        ae += e0v + e1v;
    }
    if (i < end) {
        const int e0 = eo[i];
        const int s0 = srcv[e0];
        const float2 v0 = *(const float2*)(hcol + (size_t)s0 * INF);
        ax += v0.x;
        ay += v0.y;
        if (lane < EF) ae += eftr[(size_t)e0 * EF + lane];
    }

    const int deg = end - start;
    const float inv = 1.f / fmaxf((float)deg, 1.f);
    *(float2*)(mean_h + (size_t)node * INF + lane * 2) = make_float2(ax * inv, ay * inv);
    if (lane < EF) mean_e[(size_t)node * EF + lane] = ae * inv;
}

// ---------------------------------------------------------------------------
// Node GEMM: out[n][j] = sum_r X[n][r] * M[r][j] + c[j]
//   X[n][r] = h[n][r]          r in [0,128)
//           = mean_h[n][r-128] r in [128,256)
//           = mean_e[n][r-256] r in [256,288)
// Tile: 64 nodes x 128 cols per block, 256 threads, thread = 8 nodes x 4 cols.
// ---------------------------------------------------------------------------
__global__ __launch_bounds__(256)
void node_gemm_kernel(const float* __restrict__ h,
                      const float* __restrict__ mean_h,
                      const float* __restrict__ mean_e,
                      const float* __restrict__ Mmat,
                      const float* __restrict__ cvec,
                      float* __restrict__ out) {
    __shared__ float Xs[32][64];    // [k][node]
    __shared__ float Ms[32][128];   // [k][col]

    const int tid = threadIdx.x;
    const int n0 = blockIdx.x * 64;

    const int lq = tid & 7;     // float4 group within 32-k chunk
    const int lr = tid >> 3;    // node 0..31 (plus +32 second half)
    const int tcol = tid & 31;  // col quad -> cols tcol*4..+3
    const int trow = tid >> 5;  // node octet -> nodes trow*8..+7

    float acc[8][4] = {};

    for (int kb = 0; kb < 9; ++kb) {
        // ---- stage X chunk (transposed into k-major LDS) ----
#pragma unroll
        for (int half = 0; half < 2; ++half) {
            const int nn = lr + half * 32;
            const int n = n0 + nn;
            float4 v = make_float4(0.f, 0.f, 0.f, 0.f);
            if (n < NN) {
                const float* srcp;
                if (kb < 4) {
                    srcp = h + (size_t)n * INF + kb * 32;
                } else if (kb < 8) {
                    srcp = mean_h + (size_t)n * INF + (kb - 4) * 32;
                } else {
                    srcp = mean_e + (size_t)n * EF;
                }
                v = ((const float4*)srcp)[lq];
            }
            Xs[lq * 4 + 0][nn] = v.x;
            Xs[lq * 4 + 1][nn] = v.y;
            Xs[lq * 4 + 2][nn] = v.z;
            Xs[lq * 4 + 3][nn] = v.w;
        }
        // ---- stage M chunk: 32 rows x 128 cols = 1024 float4 ----
        {
            const float4* mg = (const float4*)(Mmat + (size_t)kb * 32 * OUTF);
            float4* ms = (float4*)(&Ms[0][0]);
#pragma unroll
            for (int t = 0; t < 4; ++t)
                ms[tid + t * 256] = mg[tid + t * 256];
        }
        __syncthreads();

#pragma unroll
        for (int kk = 0; kk < 32; ++kk) {
            const float4 a0 = *(const float4*)&Xs[kk][trow * 8];
            const float4 a1 = *(const float4*)&Xs[kk][trow * 8 + 4];
            const float4 bv = *(const float4*)&Ms[kk][tcol * 4];
            const float a[8] = {a0.x, a0.y, a0.z, a0.w, a1.x, a1.y, a1.z, a1.w};
            const float b[4] = {bv.x, bv.y, bv.z, bv.w};
#pragma unroll
            for (int i = 0; i < 8; ++i)
#pragma unroll
                for (int j = 0; j < 4; ++j)
                    acc[i][j] += a[i] * b[j];
        }
        __syncthreads();
    }

    const float4 cv = *(const float4*)&cvec[tcol * 4];
#pragma unroll
    for (int i = 0; i < 8; ++i) {
        const int n = n0 + trow * 8 + i;
        if (n < NN) {
            float4 o;
            o.x = acc[i][0] + cv.x;
            o.y = acc[i][1] + cv.y;
            o.z = acc[i][2] + cv.z;
            o.w = acc[i][3] + cv.w;
            *(float4*)&out[(size_t)n * OUTF + tcol * 4] = o;
        }
    }
}

extern "C" void kernel_launch(void* const* d_in, const int* in_sizes, int n_in,
                              void* d_out, int out_size, void* d_ws, size_t ws_size,
                              hipStream_t stream) {
    const float* h      = (const float*)d_in[0];
    const float* eftr   = (const float*)d_in[1];
    const float* weight = (const float*)d_in[2];
    const float* W_w    = (const float*)d_in[3];
    const float* W_b    = (const float*)d_in[4];
    const float* bias   = (const float*)d_in[5];
    const int*   src    = (const int*)d_in[6];
    const int*   dst    = (const int*)d_in[7];
    float* out = (float*)d_out;

    // workspace layout (floats/ints, 4B each):
    float* ws     = (float*)d_ws;
    float* mean_h = ws;                               // NN*128      = 6.40M
    float* mean_e = mean_h + (size_t)NN * INF;        // NN*32       = 1.60M
    float* Mmat   = mean_e + (size_t)NN * EF;         // 288*128     = 36864
    float* cvec   = Mmat + (size_t)KDIM * OUTF;       // 128
    int*   off    = (int*)(cvec + OUTF);              // NN          = 50000
    int*   eo     = off + NN;                         // NE          = 800000
    // total ~ 8.89M * 4B = ~35.5 MB

    // zero only the histogram
    hipMemsetAsync(off, 0, (size_t)NN * sizeof(int), stream);

    prep_kernel<<<KDIM + 1, 128, 0, stream>>>(weight, W_w, W_b, bias, Mmat, cvec);
    hist_kernel<<<(NE + 255) / 256, 256, 0, stream>>>(dst, off);
    scan_kernel<<<1, 1024, 0, stream>>>(off);
    scatter_ids_kernel<<<(NE + 255) / 256, 256, 0, stream>>>(dst, off, eo);
    gather_kernel<<<(NN + 3) / 4, 256, 0, stream>>>(h, eftr, src, off, eo,
                                                    mean_h, mean_e);
    node_gemm_kernel<<<(NN + 63) / 64, 256, 0, stream>>>(h, mean_h, mean_e,
                                                         Mmat, cvec, out);
}

// Round 3
// 423.243 us; speedup vs baseline: 4.5429x; 1.2255x over previous
//
#include <hip/hip_runtime.h>

#define NN   50000
#define NE   800000
#define INF  128
#define EF   32
#define OUTF 128
#define KDIM 288   // 128 (h) + 128 (mean_h) + 32 (mean_e)

// ---------------------------------------------------------------------------
// Prep: build fused matrix M (288x128) and bias vector c (128).
//   rows 0..127   : M[f][j]     = W_w[j][f]                         (h_dst)
//   rows 128..287 : M[128+m][j] = sum_k weight[m][k]*W_w[j][128+k]  (h_neigh)
//   c[j] = W_b[j] + bias[j]
// ---------------------------------------------------------------------------
__global__ void prep_kernel(const float* __restrict__ weight,
                            const float* __restrict__ W_w,
                            const float* __restrict__ W_b,
                            const float* __restrict__ bias,
                            float* __restrict__ Mmat,
                            float* __restrict__ cvec) {
    __shared__ float wrow[OUTF];
    const int r = blockIdx.x;
    const int j = threadIdx.x;
    if (r < 128) {
        Mmat[r * OUTF + j] = W_w[j * 256 + r];
        return;
    }
    if (r == KDIM) {
        cvec[j] = W_b[j] + bias[j];
        return;
    }
    const int m = r - 128;
    wrow[j] = weight[m * OUTF + j];
    __syncthreads();
    float acc = 0.f;
#pragma unroll 8
    for (int k = 0; k < OUTF; ++k)
        acc += wrow[k] * W_w[j * 256 + 128 + k];
    Mmat[r * OUTF + j] = acc;
}

// ---------------------------------------------------------------------------
// CSR build step 1: histogram of dst into off[0..NN-1] (pre-zeroed)
// ---------------------------------------------------------------------------
__global__ __launch_bounds__(256)
void hist_kernel(const int* __restrict__ dst, int* __restrict__ off) {
    const int e = blockIdx.x * 256 + threadIdx.x;
    if (e < NE) atomicAdd(&off[dst[e]], 1);
}

// ---------------------------------------------------------------------------
// CSR build step 2: in-place exclusive scan (single block, shuffle-based).
// 1024 threads = 16 waves; per 1024-chunk: wave shfl-scan (6 steps) +
// 16-wide inter-wave scan + carry. 3 barriers per chunk.
// ---------------------------------------------------------------------------
__global__ __launch_bounds__(1024)
void scan_kernel(int* __restrict__ off) {
    __shared__ int wsum[16];
    __shared__ int carry_s;
    const int tid = threadIdx.x;
    const int lane = tid & 63;
    const int wid = tid >> 6;
    if (tid == 0) carry_s = 0;
    __syncthreads();
    for (int base = 0; base < NN; base += 1024) {
        const int idx = base + tid;
        const int v = (idx < NN) ? off[idx] : 0;
        int x = v;
#pragma unroll
        for (int ofs = 1; ofs < 64; ofs <<= 1) {
            const int t = __shfl_up(x, ofs);
            if (lane >= ofs) x += t;
        }
        if (lane == 63) wsum[wid] = x;
        __syncthreads();
        if (wid == 0) {
            int ws = (lane < 16) ? wsum[lane] : 0;
#pragma unroll
            for (int ofs = 1; ofs < 16; ofs <<= 1) {
                const int t = __shfl_up(ws, ofs);
                if (lane >= ofs) ws += t;
            }
            if (lane < 16) wsum[lane] = ws;
        }
        __syncthreads();
        const int waveprefix = (wid == 0) ? 0 : wsum[wid - 1];
        const int incl = x + waveprefix + carry_s;
        if (idx < NN) off[idx] = incl - v;   // exclusive
        __syncthreads();
        if (tid == 1023) carry_s = incl;
        __syncthreads();
    }
}

// ---------------------------------------------------------------------------
// CSR build step 3: scatter {src,edge} pairs. Cursor trick: afterwards
// off[d] == end offset of segment d (start = off[d-1]).
// ---------------------------------------------------------------------------
__global__ __launch_bounds__(256)
void scatter_ids_kernel(const int* __restrict__ srcv,
                        const int* __restrict__ dst,
                        int* __restrict__ off,
                        int2* __restrict__ eo2) {
    const int e = blockIdx.x * 256 + threadIdx.x;
    if (e < NE) {
        const int d = dst[e];
        const int pos = atomicAdd(&off[d], 1);
        eo2[pos] = make_int2(srcv[e], e);
    }
}

// ---------------------------------------------------------------------------
// Gather: one wave per node. Lane l stages eo2[start+l] (ONE coalesced
// dwordx2 per 64 edges), per-edge indices come from __shfl — no per-edge
// index loads, chain depth 1 (just the h/eftr row loads), unroll-4 keeps
// 8 loads in flight. Writes mean_h/mean_e scaled by 1/deg.
// ---------------------------------------------------------------------------
__global__ __launch_bounds__(256)
void gather_kernel(const float* __restrict__ h,
                   const float* __restrict__ eftr,
                   const int* __restrict__ off,   // end offsets
                   const int2* __restrict__ eo2,
                   float* __restrict__ mean_h,
                   float* __restrict__ mean_e) {
    const int tid = threadIdx.x;
    const int lane = tid & 63;
    const int node = blockIdx.x * 4 + (tid >> 6);
    if (node >= NN) return;

    const int end = off[node];
    const int start = (node == 0) ? 0 : off[node - 1];

    float ax = 0.f, ay = 0.f, ae = 0.f;
    const float* hcol = h + lane * 2;
    const bool elane = (lane < EF);

    for (int base = start; base < end; base += 64) {
        const int m = min(64, end - base);
        int2 p = make_int2(0, 0);
        if (base + lane < end) p = eo2[base + lane];
        int j = 0;
        for (; j + 3 < m; j += 4) {
            const int s0 = __shfl(p.x, j),     e0 = __shfl(p.y, j);
            const int s1 = __shfl(p.x, j + 1), e1 = __shfl(p.y, j + 1);
            const int s2 = __shfl(p.x, j + 2), e2 = __shfl(p.y, j + 2);
            const int s3 = __shfl(p.x, j + 3), e3 = __shfl(p.y, j + 3);
            const float2 v0 = *(const float2*)(hcol + (size_t)s0 * INF);
            const float2 v1 = *(const float2*)(hcol + (size_t)s1 * INF);
            const float2 v2 = *(const float2*)(hcol + (size_t)s2 * INF);
            const float2 v3 = *(const float2*)(hcol + (size_t)s3 * INF);
            float f0 = 0.f, f1 = 0.f, f2 = 0.f, f3 = 0.f;
            if (elane) {
                f0 = eftr[(size_t)e0 * EF + lane];
                f1 = eftr[(size_t)e1 * EF + lane];
                f2 = eftr[(size_t)e2 * EF + lane];
                f3 = eftr[(size_t)e3 * EF + lane];
            }
            ax += v0.x + v1.x + v2.x + v3.x;
            ay += v0.y + v1.y + v2.y + v3.y;
            ae += f0 + f1 + f2 + f3;
        }
        for (; j < m; ++j) {
            const int s0 = __shfl(p.x, j), e0 = __shfl(p.y, j);
            const float2 v0 = *(const float2*)(hcol + (size_t)s0 * INF);
            ax += v0.x;
            ay += v0.y;
            if (elane) ae += eftr[(size_t)e0 * EF + lane];
        }
    }

    const float inv = 1.f / fmaxf((float)(end - start), 1.f);
    *(float2*)(mean_h + (size_t)node * INF + lane * 2) =
        make_float2(ax * inv, ay * inv);
    if (elane) mean_e[(size_t)node * EF + lane] = ae * inv;
}

// ---------------------------------------------------------------------------
// Node GEMM: out[n][j] = sum_r X[n][r] * M[r][j] + c[j]
// Tile: 64 nodes x 128 cols per block, 256 threads, thread = 8 nodes x 4 cols.
// ---------------------------------------------------------------------------
__global__ __launch_bounds__(256)
void node_gemm_kernel(const float* __restrict__ h,
                      const float* __restrict__ mean_h,
                      const float* __restrict__ mean_e,
                      const float* __restrict__ Mmat,
                      const float* __restrict__ cvec,
                      float* __restrict__ out) {
    __shared__ float Xs[32][64];    // [k][node]
    __shared__ float Ms[32][128];   // [k][col]

    const int tid = threadIdx.x;
    const int n0 = blockIdx.x * 64;

    const int lq = tid & 7;     // float4 group within 32-k chunk
    const int lr = tid >> 3;    // node 0..31 (plus +32 second half)
    const int tcol = tid & 31;  // col quad -> cols tcol*4..+3
    const int trow = tid >> 5;  // node octet -> nodes trow*8..+7

    float acc[8][4] = {};

    for (int kb = 0; kb < 9; ++kb) {
#pragma unroll
        for (int half = 0; half < 2; ++half) {
            const int nn = lr + half * 32;
            const int n = n0 + nn;
            float4 v = make_float4(0.f, 0.f, 0.f, 0.f);
            if (n < NN) {
                const float* srcp;
                if (kb < 4) {
                    srcp = h + (size_t)n * INF + kb * 32;
                } else if (kb < 8) {
                    srcp = mean_h + (size_t)n * INF + (kb - 4) * 32;
                } else {
                    srcp = mean_e + (size_t)n * EF;
                }
                v = ((const float4*)srcp)[lq];
            }
            Xs[lq * 4 + 0][nn] = v.x;
            Xs[lq * 4 + 1][nn] = v.y;
            Xs[lq * 4 + 2][nn] = v.z;
            Xs[lq * 4 + 3][nn] = v.w;
        }
        {
            const float4* mg = (const float4*)(Mmat + (size_t)kb * 32 * OUTF);
            float4* ms = (float4*)(&Ms[0][0]);
#pragma unroll
            for (int t = 0; t < 4; ++t)
                ms[tid + t * 256] = mg[tid + t * 256];
        }
        __syncthreads();

#pragma unroll
        for (int kk = 0; kk < 32; ++kk) {
            const float4 a0 = *(const float4*)&Xs[kk][trow * 8];
            const float4 a1 = *(const float4*)&Xs[kk][trow * 8 + 4];
            const float4 bv = *(const float4*)&Ms[kk][tcol * 4];
            const float a[8] = {a0.x, a0.y, a0.z, a0.w, a1.x, a1.y, a1.z, a1.w};
            const float b[4] = {bv.x, bv.y, bv.z, bv.w};
#pragma unroll
            for (int i = 0; i < 8; ++i)
#pragma unroll
                for (int j = 0; j < 4; ++j)
                    acc[i][j] += a[i] * b[j];
        }
        __syncthreads();
    }

    const float4 cv = *(const float4*)&cvec[tcol * 4];
#pragma unroll
    for (int i = 0; i < 8; ++i) {
        const int n = n0 + trow * 8 + i;
        if (n < NN) {
            float4 o;
            o.x = acc[i][0] + cv.x;
            o.y = acc[i][1] + cv.y;
            o.z = acc[i][2] + cv.z;
            o.w = acc[i][3] + cv.w;
            *(float4*)&out[(size_t)n * OUTF + tcol * 4] = o;
        }
    }
}

extern "C" void kernel_launch(void* const* d_in, const int* in_sizes, int n_in,
                              void* d_out, int out_size, void* d_ws, size_t ws_size,
                              hipStream_t stream) {
    const float* h      = (const float*)d_in[0];
    const float* eftr   = (const float*)d_in[1];
    const float* weight = (const float*)d_in[2];
    const float* W_w    = (const float*)d_in[3];
    const float* W_b    = (const float*)d_in[4];
    const float* bias   = (const float*)d_in[5];
    const int*   src    = (const int*)d_in[6];
    const int*   dst    = (const int*)d_in[7];
    float* out = (float*)d_out;

    // workspace layout (4B elements):
    float* ws     = (float*)d_ws;
    float* mean_h = ws;                               // NN*128 = 6.40M
    float* mean_e = mean_h + (size_t)NN * INF;        // NN*32  = 1.60M
    float* Mmat   = mean_e + (size_t)NN * EF;         // 288*128
    float* cvec   = Mmat + (size_t)KDIM * OUTF;       // 128
    int*   off    = (int*)(cvec + OUTF);              // NN
    int2*  eo2    = (int2*)(off + NN);                // NE int2 (8B-aligned)
    // total ≈ 38.7 MB

    hipMemsetAsync(off, 0, (size_t)NN * sizeof(int), stream);

    prep_kernel<<<KDIM + 1, 128, 0, stream>>>(weight, W_w, W_b, bias, Mmat, cvec);
    hist_kernel<<<(NE + 255) / 256, 256, 0, stream>>>(dst, off);
    scan_kernel<<<1, 1024, 0, stream>>>(off);
    scatter_ids_kernel<<<(NE + 255) / 256, 256, 0, stream>>>(src, dst, off, eo2);
    gather_kernel<<<(NN + 3) / 4, 256, 0, stream>>>(h, eftr, off, eo2,
                                                    mean_h, mean_e);
    node_gemm_kernel<<<(NN + 63) / 64, 256, 0, stream>>>(h, mean_h, mean_e,
                                                         Mmat, cvec, out);
}

// Round 4
// 379.084 us; speedup vs baseline: 5.0721x; 1.1165x over previous
//
#include <hip/hip_runtime.h>

#define NN   50000
#define NE   800000
#define INF  128
#define EF   32
#define OUTF 128
#define KDIM 288   // 128 (h) + 128 (mean_h) + 32 (mean_e)
#define NBLK ((NN + 1023) / 1024)   // 49 scan blocks

// ---------------------------------------------------------------------------
// Prep: build fused matrix M (288x128) and bias vector c (128).
//   rows 0..127   : M[f][j]     = W_w[j][f]                         (h_dst)
//   rows 128..287 : M[128+m][j] = sum_k weight[m][k]*W_w[j][128+k]  (h_neigh)
//   c[j] = W_b[j] + bias[j]
// ---------------------------------------------------------------------------
__global__ void prep_kernel(const float* __restrict__ weight,
                            const float* __restrict__ W_w,
                            const float* __restrict__ W_b,
                            const float* __restrict__ bias,
                            float* __restrict__ Mmat,
                            float* __restrict__ cvec) {
    __shared__ float wrow[OUTF];
    const int r = blockIdx.x;
    const int j = threadIdx.x;
    if (r < 128) {
        Mmat[r * OUTF + j] = W_w[j * 256 + r];
        return;
    }
    if (r == KDIM) {
        cvec[j] = W_b[j] + bias[j];
        return;
    }
    const int m = r - 128;
    wrow[j] = weight[m * OUTF + j];
    __syncthreads();
    float acc = 0.f;
#pragma unroll 8
    for (int k = 0; k < OUTF; ++k)
        acc += wrow[k] * W_w[j * 256 + 128 + k];
    Mmat[r * OUTF + j] = acc;
}

// ---------------------------------------------------------------------------
// CSR build step 1: histogram of dst into off[0..NN-1] (pre-zeroed)
// ---------------------------------------------------------------------------
__global__ __launch_bounds__(256)
void hist_kernel(const int* __restrict__ dst, int* __restrict__ off) {
    const int e = blockIdx.x * 256 + threadIdx.x;
    if (e < NE) atomicAdd(&off[dst[e]], 1);
}

// ---------------------------------------------------------------------------
// CSR scan, 3-phase parallel (replaces the serial single-block scan).
// Phase 1: per-block (1024 elems) sum -> partial[b]
// ---------------------------------------------------------------------------
__global__ __launch_bounds__(256)
void scan1_kernel(const int* __restrict__ off, int* __restrict__ partial) {
    const int b = blockIdx.x;
    const int tid = threadIdx.x;
    const int idx = b * 1024 + tid * 4;
    int v0 = 0, v1 = 0, v2 = 0, v3 = 0;
    if (idx + 3 < NN) {
        const int4 q = *(const int4*)(off + idx);
        v0 = q.x; v1 = q.y; v2 = q.z; v3 = q.w;
    } else {
        if (idx + 0 < NN) v0 = off[idx + 0];
        if (idx + 1 < NN) v1 = off[idx + 1];
        if (idx + 2 < NN) v2 = off[idx + 2];
    }
    int t = v0 + v1 + v2 + v3;
#pragma unroll
    for (int ofs = 32; ofs > 0; ofs >>= 1) t += __shfl_down(t, ofs);
    __shared__ int wsum[4];
    if ((tid & 63) == 0) wsum[tid >> 6] = t;
    __syncthreads();
    if (tid == 0) partial[b] = wsum[0] + wsum[1] + wsum[2] + wsum[3];
}

// Phase 2: exclusive scan of the 49 partials (one wave)
__global__ void scan2_kernel(int* __restrict__ partial) {
    const int lane = threadIdx.x;
    const int v = (lane < NBLK) ? partial[lane] : 0;
    int x = v;
#pragma unroll
    for (int ofs = 1; ofs < 64; ofs <<= 1) {
        const int t = __shfl_up(x, ofs);
        if (lane >= ofs) x += t;
    }
    if (lane < NBLK) partial[lane] = x - v;   // exclusive
}

// Phase 3: per-block local exclusive scan + carry; in-place rewrite of off.
__global__ __launch_bounds__(256)
void scan3_kernel(int* __restrict__ off, const int* __restrict__ partial) {
    const int b = blockIdx.x;
    const int tid = threadIdx.x;
    const int lane = tid & 63;
    const int wid = tid >> 6;
    const int idx = b * 1024 + tid * 4;
    int v0 = 0, v1 = 0, v2 = 0, v3 = 0;
    if (idx + 3 < NN) {
        const int4 q = *(const int4*)(off + idx);
        v0 = q.x; v1 = q.y; v2 = q.z; v3 = q.w;
    } else {
        if (idx + 0 < NN) v0 = off[idx + 0];
        if (idx + 1 < NN) v1 = off[idx + 1];
        if (idx + 2 < NN) v2 = off[idx + 2];
    }
    const int tsum = v0 + v1 + v2 + v3;
    int x = tsum;
#pragma unroll
    for (int ofs = 1; ofs < 64; ofs <<= 1) {
        const int t = __shfl_up(x, ofs);
        if (lane >= ofs) x += t;
    }
    __shared__ int wsum[4];
    if (lane == 63) wsum[wid] = x;
    __syncthreads();
    int wp = 0;
    for (int w = 0; w < wid; ++w) wp += wsum[w];
    const int base = partial[b] + wp + (x - tsum);
    if (idx + 0 < NN) off[idx + 0] = base;
    if (idx + 1 < NN) off[idx + 1] = base + v0;
    if (idx + 2 < NN) off[idx + 2] = base + v0 + v1;
    if (idx + 3 < NN) off[idx + 3] = base + v0 + v1 + v2;
}

// ---------------------------------------------------------------------------
// CSR build step 3: scatter {src,edge} pairs. Cursor trick: afterwards
// off[d] == end offset of segment d (start = off[d-1]).
// ---------------------------------------------------------------------------
__global__ __launch_bounds__(256)
void scatter_ids_kernel(const int* __restrict__ srcv,
                        const int* __restrict__ dst,
                        int* __restrict__ off,
                        int2* __restrict__ eo2) {
    const int e = blockIdx.x * 256 + threadIdx.x;
    if (e < NE) {
        const int d = dst[e];
        const int pos = atomicAdd(&off[d], 1);
        eo2[pos] = make_int2(srcv[e], e);
    }
}

// ---------------------------------------------------------------------------
// Gather: one wave per node. Lane l stages eo2[start+l]; per-edge ids
// broadcast via readlane (wave-uniform index -> SGPR, cheap addressing).
// Unroll-8 h rows in flight; eftr uses ALL 64 lanes (low half = even edge,
// high half = odd edge), folded with one shfl at the end.
// ---------------------------------------------------------------------------
__global__ __launch_bounds__(256)
void gather_kernel(const float* __restrict__ h,
                   const float* __restrict__ eftr,
                   const int* __restrict__ off,   // end offsets
                   const int2* __restrict__ eo2,
                   float* __restrict__ mean_h,
                   float* __restrict__ mean_e) {
    const int tid = threadIdx.x;
    const int lane = tid & 63;
    const int node = blockIdx.x * 4 + (tid >> 6);
    if (node >= NN) return;

    const int end = off[node];
    const int start = (node == 0) ? 0 : off[node - 1];

    float ax = 0.f, ay = 0.f, ae = 0.f;
    const float* hcol = h + lane * 2;
    const int el = lane & 31;
    const bool lowhalf = (lane < 32);

    for (int base = start; base < end; base += 64) {
        const int m = min(64, end - base);
        int2 p = make_int2(0, 0);
        if (base + lane < end) p = eo2[base + lane];
        int j = 0;
        for (; j + 7 < m; j += 8) {
            int s[8], e[8];
#pragma unroll
            for (int u = 0; u < 8; ++u) {
                s[u] = __builtin_amdgcn_readlane(p.x, j + u);
                e[u] = __builtin_amdgcn_readlane(p.y, j + u);
            }
            float2 v[8];
#pragma unroll
            for (int u = 0; u < 8; ++u)
                v[u] = *(const float2*)(hcol + (size_t)s[u] * INF);
            float f[4];
#pragma unroll
            for (int u = 0; u < 4; ++u) {
                const int ee = lowhalf ? e[2 * u] : e[2 * u + 1];
                f[u] = eftr[(size_t)ee * EF + el];
            }
#pragma unroll
            for (int u = 0; u < 8; ++u) { ax += v[u].x; ay += v[u].y; }
            ae += (f[0] + f[1]) + (f[2] + f[3]);
        }
        for (; j < m; ++j) {
            const int s0 = __builtin_amdgcn_readlane(p.x, j);
            const int e0 = __builtin_amdgcn_readlane(p.y, j);
            const float2 v0 = *(const float2*)(hcol + (size_t)s0 * INF);
            ax += v0.x;
            ay += v0.y;
            if (lowhalf) ae += eftr[(size_t)e0 * EF + el];
        }
    }

    // fold the high-half (odd-edge) eftr accumulation into the low half
    ae += __shfl(ae, lane + 32);   // pairwise swap-add; lanes<32 now hold totals

    const float inv = 1.f / fmaxf((float)(end - start), 1.f);
    *(float2*)(mean_h + (size_t)node * INF + lane * 2) =
        make_float2(ax * inv, ay * inv);
    if (lowhalf) mean_e[(size_t)node * EF + el] = ae * inv;
}

// ---------------------------------------------------------------------------
// Node GEMM: out[n][j] = sum_r X[n][r] * M[r][j] + c[j]
// Tile: 64 nodes x 128 cols per block, 256 threads, thread = 8 nodes x 4 cols.
// ---------------------------------------------------------------------------
__global__ __launch_bounds__(256)
void node_gemm_kernel(const float* __restrict__ h,
                      const float* __restrict__ mean_h,
                      const float* __restrict__ mean_e,
                      const float* __restrict__ Mmat,
                      const float* __restrict__ cvec,
                      float* __restrict__ out) {
    __shared__ float Xs[32][64];    // [k][node]
    __shared__ float Ms[32][128];   // [k][col]

    const int tid = threadIdx.x;
    const int n0 = blockIdx.x * 64;

    const int lq = tid & 7;     // float4 group within 32-k chunk
    const int lr = tid >> 3;    // node 0..31 (plus +32 second half)
    const int tcol = tid & 31;  // col quad -> cols tcol*4..+3
    const int trow = tid >> 5;  // node octet -> nodes trow*8..+7

    float acc[8][4] = {};

    for (int kb = 0; kb < 9; ++kb) {
#pragma unroll
        for (int half = 0; half < 2; ++half) {
            const int nn = lr + half * 32;
            const int n = n0 + nn;
            float4 v = make_float4(0.f, 0.f, 0.f, 0.f);
            if (n < NN) {
                const float* srcp;
                if (kb < 4) {
                    srcp = h + (size_t)n * INF + kb * 32;
                } else if (kb < 8) {
                    srcp = mean_h + (size_t)n * INF + (kb - 4) * 32;
                } else {
                    srcp = mean_e + (size_t)n * EF;
                }
                v = ((const float4*)srcp)[lq];
            }
            Xs[lq * 4 + 0][nn] = v.x;
            Xs[lq * 4 + 1][nn] = v.y;
            Xs[lq * 4 + 2][nn] = v.z;
            Xs[lq * 4 + 3][nn] = v.w;
        }
        {
            const float4* mg = (const float4*)(Mmat + (size_t)kb * 32 * OUTF);
            float4* ms = (float4*)(&Ms[0][0]);
#pragma unroll
            for (int t = 0; t < 4; ++t)
                ms[tid + t * 256] = mg[tid + t * 256];
        }
        __syncthreads();

#pragma unroll
        for (int kk = 0; kk < 32; ++kk) {
            const float4 a0 = *(const float4*)&Xs[kk][trow * 8];
            const float4 a1 = *(const float4*)&Xs[kk][trow * 8 + 4];
            const float4 bv = *(const float4*)&Ms[kk][tcol * 4];
            const float a[8] = {a0.x, a0.y, a0.z, a0.w, a1.x, a1.y, a1.z, a1.w};
            const float b[4] = {bv.x, bv.y, bv.z, bv.w};
#pragma unroll
            for (int i = 0; i < 8; ++i)
#pragma unroll
                for (int j = 0; j < 4; ++j)
                    acc[i][j] += a[i] * b[j];
        }
        __syncthreads();
    }

    const float4 cv = *(const float4*)&cvec[tcol * 4];
#pragma unroll
    for (int i = 0; i < 8; ++i) {
        const int n = n0 + trow * 8 + i;
        if (n < NN) {
            float4 o;
            o.x = acc[i][0] + cv.x;
            o.y = acc[i][1] + cv.y;
            o.z = acc[i][2] + cv.z;
            o.w = acc[i][3] + cv.w;
            *(float4*)&out[(size_t)n * OUTF + tcol * 4] = o;
        }
    }
}

extern "C" void kernel_launch(void* const* d_in, const int* in_sizes, int n_in,
                              void* d_out, int out_size, void* d_ws, size_t ws_size,
                              hipStream_t stream) {
    const float* h      = (const float*)d_in[0];
    const float* eftr   = (const float*)d_in[1];
    const float* weight = (const float*)d_in[2];
    const float* W_w    = (const float*)d_in[3];
    const float* W_b    = (const float*)d_in[4];
    const float* bias   = (const float*)d_in[5];
    const int*   src    = (const int*)d_in[6];
    const int*   dst    = (const int*)d_in[7];
    float* out = (float*)d_out;

    // workspace layout (4B elements):
    float* ws      = (float*)d_ws;
    float* mean_h  = ws;                               // NN*128 = 6.40M
    float* mean_e  = mean_h + (size_t)NN * INF;        // NN*32  = 1.60M
    float* Mmat    = mean_e + (size_t)NN * EF;         // 288*128
    float* cvec    = Mmat + (size_t)KDIM * OUTF;       // 128
    int*   off     = (int*)(cvec + OUTF);              // NN (16B-aligned)
    int2*  eo2     = (int2*)(off + NN);                // NE int2
    int*   partial = (int*)(eo2 + NE);                 // NBLK
    // total ≈ 38.7 MB

    hipMemsetAsync(off, 0, (size_t)NN * sizeof(int), stream);

    prep_kernel<<<KDIM + 1, 128, 0, stream>>>(weight, W_w, W_b, bias, Mmat, cvec);
    hist_kernel<<<(NE + 255) / 256, 256, 0, stream>>>(dst, off);
    scan1_kernel<<<NBLK, 256, 0, stream>>>(off, partial);
    scan2_kernel<<<1, 64, 0, stream>>>(partial);
    scan3_kernel<<<NBLK, 256, 0, stream>>>(off, partial);
    scatter_ids_kernel<<<(NE + 255) / 256, 256, 0, stream>>>(src, dst, off, eo2);
    gather_kernel<<<(NN + 3) / 4, 256, 0, stream>>>(h, eftr, off, eo2,
                                                    mean_h, mean_e);
    node_gemm_kernel<<<(NN + 63) / 64, 256, 0, stream>>>(h, mean_h, mean_e,
                                                         Mmat, cvec, out);
}

// Round 5
// 341.356 us; speedup vs baseline: 5.6327x; 1.1105x over previous
//
#include <hip/hip_runtime.h>

#define NN   50000
#define NE   800000
#define INF  128
#define EF   32
#define OUTF 128
#define KDIM 288   // 128 (h) + 128 (mean_h) + 32 (mean_e)
#define NBLK ((NN + 1023) / 1024)   // 49 scan blocks

typedef __attribute__((ext_vector_type(8))) short     short8;   // 8 bf16
typedef __attribute__((ext_vector_type(8))) unsigned short ushort8;
typedef __attribute__((ext_vector_type(4))) float     float4v;

__device__ __forceinline__ unsigned short f2bf(float f) {
    union { float f; unsigned int u; } c; c.f = f;
    const unsigned int r = (c.u + 0x7FFFu + ((c.u >> 16) & 1u)) >> 16;
    return (unsigned short)r;
}

// ---------------------------------------------------------------------------
// Prep: build fused matrix M (288x128) fp32 and bias vector c (128).
//   rows 0..127   : M[f][j]     = W_w[j][f]                         (h_dst)
//   rows 128..287 : M[128+m][j] = sum_k weight[m][k]*W_w[j][128+k]  (h_neigh)
//   c[j] = W_b[j] + bias[j]
// ---------------------------------------------------------------------------
__global__ void prep_kernel(const float* __restrict__ weight,
                            const float* __restrict__ W_w,
                            const float* __restrict__ W_b,
                            const float* __restrict__ bias,
                            float* __restrict__ Mmat,
                            float* __restrict__ cvec) {
    __shared__ float wrow[OUTF];
    const int r = blockIdx.x;
    const int j = threadIdx.x;
    if (r < 128) {
        Mmat[r * OUTF + j] = W_w[j * 256 + r];
        return;
    }
    if (r == KDIM) {
        cvec[j] = W_b[j] + bias[j];
        return;
    }
    const int m = r - 128;
    wrow[j] = weight[m * OUTF + j];
    __syncthreads();
    float acc = 0.f;
#pragma unroll 8
    for (int k = 0; k < OUTF; ++k)
        acc += wrow[k] * W_w[j * 256 + 128 + k];
    Mmat[r * OUTF + j] = acc;
}

// ---------------------------------------------------------------------------
// Pack M into bf16 MFMA B-fragment order: Mb[kb(9)][ct(8)][lane(64)][8].
// B-frag layout for mfma_f32_16x16x32_bf16: B[k=quad*8+i][n=lane&15],
// quad=lane>>4.  grid = 72 blocks x 64 threads.
// ---------------------------------------------------------------------------
__global__ void pack_kernel(const float* __restrict__ Mmat,
                            unsigned short* __restrict__ Mb) {
    const int b = blockIdx.x;          // kb*8 + ct
    const int kb = b >> 3;
    const int ct = b & 7;
    const int lane = threadIdx.x;
    const int col = ct * 16 + (lane & 15);
    const int k0 = kb * 32 + (lane >> 4) * 8;
    ushort8 v;
#pragma unroll
    for (int i = 0; i < 8; ++i)
        v[i] = f2bf(Mmat[(size_t)(k0 + i) * OUTF + col]);
    *(ushort8*)(Mb + ((size_t)(b * 64 + lane) * 8)) = v;
}

// ---------------------------------------------------------------------------
// CSR build step 1: histogram of dst into off[0..NN-1] (pre-zeroed)
// ---------------------------------------------------------------------------
__global__ __launch_bounds__(256)
void hist_kernel(const int* __restrict__ dst, int* __restrict__ off) {
    const int e = blockIdx.x * 256 + threadIdx.x;
    if (e < NE) atomicAdd(&off[dst[e]], 1);
}

// ---------------------------------------------------------------------------
// Scan phase 1: per-block (1024 elems) sum -> partial[b]
// ---------------------------------------------------------------------------
__global__ __launch_bounds__(256)
void scan1_kernel(const int* __restrict__ off, int* __restrict__ partial) {
    const int b = blockIdx.x;
    const int tid = threadIdx.x;
    const int idx = b * 1024 + tid * 4;
    int v0 = 0, v1 = 0, v2 = 0, v3 = 0;
    if (idx + 3 < NN) {
        const int4 q = *(const int4*)(off + idx);
        v0 = q.x; v1 = q.y; v2 = q.z; v3 = q.w;
    } else {
        if (idx + 0 < NN) v0 = off[idx + 0];
        if (idx + 1 < NN) v1 = off[idx + 1];
        if (idx + 2 < NN) v2 = off[idx + 2];
    }
    int t = v0 + v1 + v2 + v3;
#pragma unroll
    for (int ofs = 32; ofs > 0; ofs >>= 1) t += __shfl_down(t, ofs);
    __shared__ int wsum[4];
    if ((tid & 63) == 0) wsum[tid >> 6] = t;
    __syncthreads();
    if (tid == 0) partial[b] = wsum[0] + wsum[1] + wsum[2] + wsum[3];
}

// ---------------------------------------------------------------------------
// Scan phase 2+3 fused: every block re-scans the 49 partials in one wave
// (cheap), then does its local exclusive scan + rewrite of off.
// ---------------------------------------------------------------------------
__global__ __launch_bounds__(256)
void scan3_kernel(int* __restrict__ off, const int* __restrict__ partial) {
    __shared__ int blockbase;
    __shared__ int wsum[4];
    const int b = blockIdx.x;
    const int tid = threadIdx.x;
    const int lane = tid & 63;
    const int wid = tid >> 6;

    if (wid == 0) {
        const int v = (lane < NBLK) ? partial[lane] : 0;
        int x = v;
#pragma unroll
        for (int ofs = 1; ofs < 64; ofs <<= 1) {
            const int t = __shfl_up(x, ofs);
            if (lane >= ofs) x += t;
        }
        if (lane == b) blockbase = x - v;   // exclusive prefix of this block
    }

    const int idx = b * 1024 + tid * 4;
    int v0 = 0, v1 = 0, v2 = 0, v3 = 0;
    if (idx + 3 < NN) {
        const int4 q = *(const int4*)(off + idx);
        v0 = q.x; v1 = q.y; v2 = q.z; v3 = q.w;
    } else {
        if (idx + 0 < NN) v0 = off[idx + 0];
        if (idx + 1 < NN) v1 = off[idx + 1];
        if (idx + 2 < NN) v2 = off[idx + 2];
    }
    const int tsum = v0 + v1 + v2 + v3;
    int x = tsum;
#pragma unroll
    for (int ofs = 1; ofs < 64; ofs <<= 1) {
        const int t = __shfl_up(x, ofs);
        if (lane >= ofs) x += t;
    }
    if (lane == 63) wsum[wid] = x;
    __syncthreads();
    int wp = 0;
    for (int w = 0; w < wid; ++w) wp += wsum[w];
    const int base = blockbase + wp + (x - tsum);
    if (idx + 0 < NN) off[idx + 0] = base;
    if (idx + 1 < NN) off[idx + 1] = base + v0;
    if (idx + 2 < NN) off[idx + 2] = base + v0 + v1;
    if (idx + 3 < NN) off[idx + 3] = base + v0 + v1 + v2;
}

// ---------------------------------------------------------------------------
// CSR build step 3: scatter {src,edge} pairs. Cursor trick: afterwards
// off[d] == end offset of segment d (start = off[d-1]).
// ---------------------------------------------------------------------------
__global__ __launch_bounds__(256)
void scatter_ids_kernel(const int* __restrict__ srcv,
                        const int* __restrict__ dst,
                        int* __restrict__ off,
                        int2* __restrict__ eo2) {
    const int e = blockIdx.x * 256 + threadIdx.x;
    if (e < NE) {
        const int d = dst[e];
        const int pos = atomicAdd(&off[d], 1);
        eo2[pos] = make_int2(srcv[e], e);
    }
}

// ---------------------------------------------------------------------------
// Gather: one wave per node; readlane-broadcast indices; unroll-8 h rows.
// eo2/eftr are once-only streams -> nontemporal loads so they don't evict
// the h working set (25.6 MB) from L2 (fix for the ~100 MB h re-fetch).
// ---------------------------------------------------------------------------
__global__ __launch_bounds__(256)
void gather_kernel(const float* __restrict__ h,
                   const float* __restrict__ eftr,
                   const int* __restrict__ off,   // end offsets
                   const int2* __restrict__ eo2,
                   float* __restrict__ mean_h,
                   float* __restrict__ mean_e) {
    const int tid = threadIdx.x;
    const int lane = tid & 63;
    const int node = blockIdx.x * 4 + (tid >> 6);
    if (node >= NN) return;

    const int end = off[node];
    const int start = (node == 0) ? 0 : off[node - 1];

    float ax = 0.f, ay = 0.f, ae = 0.f;
    const float* hcol = h + lane * 2;
    const int el = lane & 31;
    const bool lowhalf = (lane < 32);

    for (int base = start; base < end; base += 64) {
        const int m = min(64, end - base);
        int px = 0, py = 0;
        if (base + lane < end) {
            const long long pv =
                __builtin_nontemporal_load((const long long*)(eo2 + base + lane));
            px = (int)pv;
            py = (int)(pv >> 32);
        }
        int j = 0;
        for (; j + 7 < m; j += 8) {
            int s[8], e[8];
#pragma unroll
            for (int u = 0; u < 8; ++u) {
                s[u] = __builtin_amdgcn_readlane(px, j + u);
                e[u] = __builtin_amdgcn_readlane(py, j + u);
            }
            float2 v[8];
#pragma unroll
            for (int u = 0; u < 8; ++u)
                v[u] = *(const float2*)(hcol + (size_t)s[u] * INF);
            float f[4];
#pragma unroll
            for (int u = 0; u < 4; ++u) {
                const int ee = lowhalf ? e[2 * u] : e[2 * u + 1];
                f[u] = __builtin_nontemporal_load(&eftr[(size_t)ee * EF + el]);
            }
#pragma unroll
            for (int u = 0; u < 8; ++u) { ax += v[u].x; ay += v[u].y; }
            ae += (f[0] + f[1]) + (f[2] + f[3]);
        }
        for (; j < m; ++j) {
            const int s0 = __builtin_amdgcn_readlane(px, j);
            const int e0 = __builtin_amdgcn_readlane(py, j);
            const float2 v0 = *(const float2*)(hcol + (size_t)s0 * INF);
            ax += v0.x;
            ay += v0.y;
            if (lowhalf) ae += __builtin_nontemporal_load(&eftr[(size_t)e0 * EF + el]);
        }
    }

    ae += __shfl(ae, lane + 32);   // fold odd-edge half into low half

    const float inv = 1.f / fmaxf((float)(end - start), 1.f);
    *(float2*)(mean_h + (size_t)node * INF + lane * 2) =
        make_float2(ax * inv, ay * inv);
    if (lowhalf) mean_e[(size_t)node * EF + el] = ae * inv;
}

// ---------------------------------------------------------------------------
// Node GEMM via MFMA (bf16 in, fp32 acc). LDS-free, barrier-free.
// Each wave owns a 16-node tile, all 128 cols, K=288 in 9 chunks of 32.
// A-frag: lane reads X[node = nt*16 + (lane&15)][k = kb*32 + (lane>>4)*8 .. +7]
//         (8 consecutive fp32 -> cvt bf16 in-register).
// B-frag: coalesced b128 from pre-packed Mb[kb][ct][lane][8].
// C/D:    lane holds D[row=(lane>>4)*4+r][col=lane&15] (verified layout).
// ---------------------------------------------------------------------------
__global__ __launch_bounds__(256)
void node_gemm_kernel(const float* __restrict__ h,
                      const float* __restrict__ mean_h,
                      const float* __restrict__ mean_e,
                      const unsigned short* __restrict__ Mb,
                      const float* __restrict__ cvec,
                      float* __restrict__ out) {
    const int tid = threadIdx.x;
    const int lane = tid & 63;
    const int wid = tid >> 6;
    const int nt = blockIdx.x * 4 + wid;     // 16-node tile id
    const int m16 = lane & 15;
    const int quad = lane >> 4;
    const int koff = quad * 8;

    const int anode = nt * 16 + m16;
    const int nclamp = (anode < NN) ? anode : (NN - 1);

    float4v acc[8] = {};

    for (int kb = 0; kb < 9; ++kb) {
        const float* srcp;
        if (kb < 4)
            srcp = h + (size_t)nclamp * INF + kb * 32 + koff;
        else if (kb < 8)
            srcp = mean_h + (size_t)nclamp * INF + (kb - 4) * 32 + koff;
        else
            srcp = mean_e + (size_t)nclamp * EF + koff;
        const float4 p0 = *(const float4*)srcp;
        const float4 p1 = *(const float4*)(srcp + 4);
        short8 a;
        a[0] = (short)f2bf(p0.x); a[1] = (short)f2bf(p0.y);
        a[2] = (short)f2bf(p0.z); a[3] = (short)f2bf(p0.w);
        a[4] = (short)f2bf(p1.x); a[5] = (short)f2bf(p1.y);
        a[6] = (short)f2bf(p1.z); a[7] = (short)f2bf(p1.w);

        const short8* bp = (const short8*)(Mb + (size_t)kb * 8 * 64 * 8);
#pragma unroll
        for (int ct = 0; ct < 8; ++ct) {
            const short8 b = bp[ct * 64 + lane];
            acc[ct] = __builtin_amdgcn_mfma_f32_16x16x32_bf16(a, b, acc[ct], 0, 0, 0);
        }
    }

    float cv[8];
#pragma unroll
    for (int ct = 0; ct < 8; ++ct) cv[ct] = cvec[ct * 16 + m16];

#pragma unroll
    for (int r = 0; r < 4; ++r) {
        const int nrow = nt * 16 + quad * 4 + r;
        if (nrow < NN) {
            float* orow = out + (size_t)nrow * OUTF;
#pragma unroll
            for (int ct = 0; ct < 8; ++ct)
                orow[ct * 16 + m16] = acc[ct][r] + cv[ct];
        }
    }
}

extern "C" void kernel_launch(void* const* d_in, const int* in_sizes, int n_in,
                              void* d_out, int out_size, void* d_ws, size_t ws_size,
                              hipStream_t stream) {
    const float* h      = (const float*)d_in[0];
    const float* eftr   = (const float*)d_in[1];
    const float* weight = (const float*)d_in[2];
    const float* W_w    = (const float*)d_in[3];
    const float* W_b    = (const float*)d_in[4];
    const float* bias   = (const float*)d_in[5];
    const int*   src    = (const int*)d_in[6];
    const int*   dst    = (const int*)d_in[7];
    float* out = (float*)d_out;

    // workspace layout (4B units unless noted):
    float* ws      = (float*)d_ws;
    float* mean_h  = ws;                                    // NN*128
    float* mean_e  = mean_h + (size_t)NN * INF;             // NN*32
    float* Mmat    = mean_e + (size_t)NN * EF;              // 288*128
    float* cvec    = Mmat + (size_t)KDIM * OUTF;            // 128
    unsigned short* Mb = (unsigned short*)(cvec + OUTF);    // 9*8*64*8 bf16 = 73728 B
    int*   off     = (int*)((char*)Mb + (size_t)9 * 8 * 64 * 8 * 2); // NN
    int2*  eo2     = (int2*)(off + NN);                     // NE int2
    int*   partial = (int*)(eo2 + NE);                      // NBLK
    // total ≈ 38.8 MB

    hipMemsetAsync(off, 0, (size_t)NN * sizeof(int), stream);

    prep_kernel<<<KDIM + 1, 128, 0, stream>>>(weight, W_w, W_b, bias, Mmat, cvec);
    pack_kernel<<<72, 64, 0, stream>>>(Mmat, Mb);
    hist_kernel<<<(NE + 255) / 256, 256, 0, stream>>>(dst, off);
    scan1_kernel<<<NBLK, 256, 0, stream>>>(off, partial);
    scan3_kernel<<<NBLK, 256, 0, stream>>>(off, partial);
    scatter_ids_kernel<<<(NE + 255) / 256, 256, 0, stream>>>(src, dst, off, eo2);
    gather_kernel<<<(NN + 3) / 4, 256, 0, stream>>>(h, eftr, off, eo2,
                                                    mean_h, mean_e);
    node_gemm_kernel<<<(NN / 64) + 1, 256, 0, stream>>>(h, mean_h, mean_e,
                                                        Mb, cvec, out);
}